// Round 5
// baseline (638.388 us; speedup 1.0000x reference)
//
#include <hip/hip_runtime.h>
#include <hip/hip_bf16.h>

#define NTOK 4096
#define DIN  1024
#define DHID 4096
#define DOUT 1024
#define NEXP 8
#define TMAX 72   // max 128-row tiles: 8192/128 + 7 partials = 71, +1 slack
#define G1BLK (TMAX * (DHID / 128))   // 2304 gemm1 blocks
#define SPLITK 2
#define KH (DHID / SPLITK)            // 2048 k per gemm2 split

typedef __hip_bfloat16 bf16;
typedef short short8 __attribute__((ext_vector_type(8)));
typedef short short4v __attribute__((ext_vector_type(4)));
typedef float floatx4 __attribute__((ext_vector_type(4)));

// s_waitcnt immediates (gfx9 encoding): vmcnt[3:0] @0, expcnt @4, lgkmcnt @8
#define WAIT_VM0 0x0F70   // vmcnt(0), lgkmcnt/expcnt = no-wait
#define WAIT_VM4 0x0F74   // vmcnt(4)

// ---- workspace layout (bytes) ----
#define WS_XB    0ull           // x bf16            [4096*1024]   8.4 MB
#define WS_W1T   8388608ull     // W1^T bf16         [8][4096][1024] 67.1 MB
#define WS_W2T   75497472ull    // W2^T bf16         [8][1024][4096] 67.1 MB
#define WS_H     142606336ull   // h bf16            [8192][4096]  67.1 MB
#define WS_META  209715200ull
// meta region offsets (cnt+cur_g adjacent -> one 64 B memset clears both)
#define MO_CNT    0     // int[8]
#define MO_CURG   32    // int[8]  (zero-based cursors; off derived from cnt)
#define MO_T2I    1536  // int[4096*2]
#define MO_T2W    34304 // float[4096*2]
#define MO_ROWS   67072 // int[8192]
#define MO_ROWW   99840 // float[8192]

// async global->LDS, 16 B per lane; LDS dest = wave-uniform base + lane*16
__device__ __forceinline__ void gload16(const bf16* g, bf16* l) {
  __builtin_amdgcn_global_load_lds(
      (const __attribute__((address_space(1))) void*)g,
      (__attribute__((address_space(3))) void*)l, 16, 0, 0);
}

// ---- tile lookup from cnt[8]: returns nt; sets e/start/mrows for `tile` ----
__device__ __forceinline__ int tile_lookup(const int* __restrict__ cnt, int tile,
                                           int& e, int& start, int& mrows) {
  int o = 0, tacc = 0;
  e = -1; start = 0; mrows = 0;
  #pragma unroll
  for (int k = 0; k < 8; k++) {
    int c = cnt[k];
    int nb = (c + 127) >> 7;
    if (e < 0 && tile < tacc + nb) {
      e = k; int r = (tile - tacc) << 7;
      start = o + r; mrows = min(128, c - r);
    }
    tacc += nb; o += c;
  }
  return tacc;
}

// ------- transpose+cast tile: in[R][C] fp32 -> out[C][R] bf16 (one 64x64) -----
// LDS t[c][r] stride 65 (odd -> 2-way alias on both phases, free). Proven r0-r3.
__device__ __forceinline__ void transpose_tile(const float* __restrict__ in,
                                               bf16* __restrict__ out,
                                               int R, int C, int cx, int ry,
                                               int e, float* t) {
  size_t ebase = (size_t)e * R * C;
  int c0 = cx * 64, r0 = ry * 64;
  int tid = threadIdx.x;
  int rr = tid >> 4;            // 0..15
  int cq = (tid & 15) * 4;      // 0,4,...,60
  #pragma unroll
  for (int i = 0; i < 4; i++) {
    int r = rr + i * 16;
    float4 v = *(const float4*)(in + ebase + (size_t)(r0 + r) * C + c0 + cq);
    t[(cq + 0) * 65 + r] = v.x; t[(cq + 1) * 65 + r] = v.y;
    t[(cq + 2) * 65 + r] = v.z; t[(cq + 3) * 65 + r] = v.w;
  }
  __syncthreads();
  int cc = tid >> 3;            // 0..31
  int rq = (tid & 7) * 8;       // 0,8,...,56
  #pragma unroll
  for (int i = 0; i < 2; i++) {
    int c = cc + i * 32;
    union { int4 v; bf16 h[8]; } u;
    #pragma unroll
    for (int j = 0; j < 8; j++) u.h[j] = __float2bfloat16(t[c * 65 + rq + j]);
    *(int4*)(out + ebase + (size_t)(c0 + c) * R + r0 + rq) = u.v;
  }
}

// ------- gating body: softmax -> top2 -> softmax(top2 probs) + x bf16 cast ----
__device__ __forceinline__ void gate_body(const float* __restrict__ x,
                                          const float* __restrict__ Wg,
                                          const float* __restrict__ bg,
                                          bf16* __restrict__ xb,
                                          int* __restrict__ t2i,
                                          float* __restrict__ t2w,
                                          int* __restrict__ cnt, int blk) {
  int wave = threadIdx.x >> 6, lane = threadIdx.x & 63;
  int t = blk * 4 + wave;
  const float* xr = x + (size_t)t * DIN;
  bf16* xbr = xb + (size_t)t * DIN;
  float acc[8] = {0.f, 0.f, 0.f, 0.f, 0.f, 0.f, 0.f, 0.f};
  #pragma unroll
  for (int i = 0; i < 4; i++) {
    int d0 = (lane + i * 64) * 4;
    float4 v = *(const float4*)(xr + d0);
    union { short4v s; bf16 h[4]; } u;
    u.h[0] = __float2bfloat16(v.x); u.h[1] = __float2bfloat16(v.y);
    u.h[2] = __float2bfloat16(v.z); u.h[3] = __float2bfloat16(v.w);
    *(short4v*)(xbr + d0) = u.s;
    float xv4[4] = {v.x, v.y, v.z, v.w};
    #pragma unroll
    for (int c = 0; c < 4; c++) {
      const float* wr = Wg + (size_t)(d0 + c) * 8;
      float4 w0 = *(const float4*)wr;
      float4 w1 = *(const float4*)(wr + 4);
      float xv = xv4[c];
      acc[0] += xv * w0.x; acc[1] += xv * w0.y; acc[2] += xv * w0.z; acc[3] += xv * w0.w;
      acc[4] += xv * w1.x; acc[5] += xv * w1.y; acc[6] += xv * w1.z; acc[7] += xv * w1.w;
    }
  }
  #pragma unroll
  for (int off = 32; off; off >>= 1) {
    #pragma unroll
    for (int e = 0; e < 8; e++) acc[e] += __shfl_xor(acc[e], off, 64);
  }
  if (lane == 0) {
    float p[8], m = -1e30f, s = 0.f;
    #pragma unroll
    for (int e = 0; e < 8; e++) { p[e] = acc[e] + bg[e]; m = fmaxf(m, p[e]); }
    #pragma unroll
    for (int e = 0; e < 8; e++) { p[e] = expf(p[e] - m); s += p[e]; }
    float inv = 1.f / s;
    #pragma unroll
    for (int e = 0; e < 8; e++) p[e] *= inv;
    int i0 = 0;
    #pragma unroll
    for (int e = 1; e < 8; e++) if (p[e] > p[i0]) i0 = e;   // ties -> lowest idx
    int i1 = (i0 == 0) ? 1 : 0;
    #pragma unroll
    for (int e = 0; e < 8; e++) if (e != i0 && p[e] > p[i1]) i1 = e;
    float d = expf(p[i1] - p[i0]);           // softmax over the two PROBABILITIES
    float w0 = 1.f / (1.f + d), w1 = d / (1.f + d);
    t2i[2 * t] = i0; t2i[2 * t + 1] = i1;
    t2w[2 * t] = w0; t2w[2 * t + 1] = w1;
    atomicAdd(&cnt[i0], 1);
    atomicAdd(&cnt[i1], 1);
  }
}

// ---- launch A: gate (blocks 0..1023) + W1 transpose (blocks 1024..9215) ----
__global__ __launch_bounds__(256)
void k_gate_w1t(const float* __restrict__ x, const float* __restrict__ Wg,
                const float* __restrict__ bg, bf16* __restrict__ xb,
                int* __restrict__ t2i, float* __restrict__ t2w,
                int* __restrict__ cnt,
                const float* __restrict__ W1, bf16* __restrict__ w1t) {
  __shared__ __align__(16) float tsm[64 * 65];
  int b = blockIdx.x;
  if (b < NTOK / 4) {
    gate_body(x, Wg, bg, xb, t2i, t2w, cnt, b);
  } else {
    int tb = b - NTOK / 4;
    int e = tb >> 10;           // 1024 blocks per expert (64 x 16)
    int rem = tb & 1023;
    int cx = rem & 63;          // over C = DHID
    int ry = rem >> 6;          // over R = DIN
    transpose_tile(W1, w1t, DIN, DHID, cx, ry, e, tsm);
  }
}

// ---- scatter: two-level (LDS rank, one global atomic per blk*exp); off derived
// from cnt in-register, cur_g is a zero-based global cursor (memset with cnt) ----
__global__ void k_scatter(const int* __restrict__ t2i, const float* __restrict__ t2w,
                          const int* __restrict__ cnt, int* __restrict__ cur_g,
                          int* __restrict__ rows, float* __restrict__ roww) {
  __shared__ int lcnt[8], lbase[8];
  if (threadIdx.x < 8) lcnt[threadIdx.x] = 0;
  __syncthreads();
  int t = blockIdx.x * 256 + threadIdx.x;
  int e0 = t2i[2 * t], e1 = t2i[2 * t + 1];
  int p0 = atomicAdd(&lcnt[e0], 1);
  int p1 = atomicAdd(&lcnt[e1], 1);
  __syncthreads();
  if (threadIdx.x < 8) {
    int base = atomicAdd(&cur_g[threadIdx.x], lcnt[threadIdx.x]);
    int off = 0;
    for (int k = 0; k < threadIdx.x; k++) off += cnt[k];
    lbase[threadIdx.x] = off + base;
  }
  __syncthreads();
  int a0 = lbase[e0] + p0, a1 = lbase[e1] + p1;
  rows[a0] = t; roww[a0] = t2w[2 * t];
  rows[a1] = t; roww[a1] = t2w[2 * t + 1];
}

// ---- grouped GEMM tile body, 128x128, BK=32, 4 waves (round-1 proven) ----
// Typed [3][4096] LDS array refs (restores round-1 codegen: VGPR 72, VALU ~12%).
// Triple-buffered, depth-2 prefetch, counted vmcnt(4), chunk-rotation swizzle
// (0 bank conflicts), XCD-chunked tile swizzle. kbase/nk support split-K.
// MODE 1: h = relu(x_gathered @ W1T^T + b1), bf16 out
// MODE 2: out[token] += w * (h @ W2T^T + [split0] b2), fp32 atomic
template <int MODE>
__device__ __forceinline__ void gemm_tile(
    const bf16* __restrict__ A, const bf16* __restrict__ Bt,
    const float* __restrict__ bias, const int* __restrict__ cnt,
    const int* __restrict__ rows, const float* __restrict__ roww,
    bf16* __restrict__ hout, float* __restrict__ out,
    int K, int N, int hwid, int kbase, int nk, bool addb,
    bf16 (&Al)[3][4096], bf16 (&Bl)[3][4096]) {
  // XCD-chunked swizzle: XCD c owns tiles [9c,9c+9) x all n-panels, panel-major.
  int xcd = hwid & 7, pos = hwid >> 3;
  int tile = xcd * 9 + pos % 9;
  int e, start, mrows;
  int ntt = tile_lookup(cnt, tile, e, start, mrows);
  if (tile >= ntt) return;   // block-uniform: no barrier divergence
  int n0 = (pos / 9) * 128;
  int tid = threadIdx.x, lane = tid & 63, wave = tid >> 6;
  int wm = wave & 1, wn = wave >> 1;

  int srow = tid >> 2;          // 0..63
  int rot = (srow >> 1) & 3;    // invariant under row+64
  int kc8 = (((tid & 3) - rot) & 3) * 8;   // swizzled source k-octet
  int ra0 = srow, ra1 = 64 + srow;
  int er0 = ra0 < mrows ? ra0 : 0;
  int er1 = ra1 < mrows ? ra1 : 0;
  size_t ga0, ga1;
  if (MODE == 1) {
    ga0 = (size_t)rows[start + er0] * K;
    ga1 = (size_t)rows[start + er1] * K;
  } else {
    ga0 = (size_t)(start + er0) * K;
    ga1 = (size_t)(start + er1) * K;
  }
  const bf16* ap0 = A + ga0 + kbase + kc8;
  const bf16* ap1 = A + ga1 + kbase + kc8;
  const bf16* bb = Bt + (size_t)e * K * N + (size_t)n0 * K + kbase;
  const bf16* bp0 = bb + (size_t)srow * K + kc8;
  const bf16* bp1 = bb + (size_t)(64 + srow) * K + kc8;

  floatx4 zz = {0.f, 0.f, 0.f, 0.f};
  floatx4 acc[4][4];
  #pragma unroll
  for (int i = 0; i < 4; i++)
    #pragma unroll
    for (int j = 0; j < 4; j++) acc[i][j] = zz;

  int fr = lane & 15;
  int ko = (((lane >> 4) + ((fr >> 1) & 3)) & 3) * 8;

#define STAGE(buf, kk)                                    \
  do {                                                    \
    gload16(ap0 + (kk), &Al[buf][tid * 8]);               \
    gload16(ap1 + (kk), &Al[buf][2048 + tid * 8]);        \
    gload16(bp0 + (kk), &Bl[buf][tid * 8]);               \
    gload16(bp1 + (kk), &Bl[buf][2048 + tid * 8]);        \
  } while (0)

  // prologue: 2 tiles in flight
  STAGE(0, 0);
  STAGE(1, 32);

  int cur = 0;
  for (int t = 0; t < nk; ++t) {
    // drain tile t's 4 loads only; tile t+1's 4 stay in flight across MFMAs
    if (t + 1 < nk) __builtin_amdgcn_s_waitcnt(WAIT_VM4);
    else            __builtin_amdgcn_s_waitcnt(WAIT_VM0);
    __builtin_amdgcn_s_barrier();

    short8 af[4], bfr[4];
    #pragma unroll
    for (int i = 0; i < 4; i++)
      af[i] = *(const short8*)&Al[cur][(wm * 64 + i * 16 + fr) * 32 + ko];
    #pragma unroll
    for (int j = 0; j < 4; j++)
      bfr[j] = *(const short8*)&Bl[cur][(wn * 64 + j * 16 + fr) * 32 + ko];

    // issue tile t+2 into buffer (cur+2)%3; WAR-safe (readers done at t-1,
    // separated by this iter's barrier)
    if (t + 2 < nk) {
      int nb = cur + 2; if (nb >= 3) nb -= 3;
      STAGE(nb, (t + 2) * 32);
    }

    #pragma unroll
    for (int i = 0; i < 4; i++)
      #pragma unroll
      for (int j = 0; j < 4; j++)
        acc[i][j] = __builtin_amdgcn_mfma_f32_16x16x32_bf16(af[i], bfr[j], acc[i][j], 0, 0, 0);
    cur = (cur + 1 == 3) ? 0 : cur + 1;
  }
#undef STAGE

  // epilogue: C/D layout col=lane&15, row=(lane>>4)*4+reg
  int col_l = lane & 15, quad = lane >> 4;
  if (MODE == 1) {
    #pragma unroll
    for (int i = 0; i < 4; i++) {
      #pragma unroll
      for (int r = 0; r < 4; r++) {
        int row = wm * 64 + i * 16 + quad * 4 + r;
        if (row < mrows) {
          size_t rb = (size_t)(start + row) * N;
          #pragma unroll
          for (int j = 0; j < 4; j++) {
            int col = n0 + wn * 64 + j * 16 + col_l;
            float v = acc[i][j][r] + bias[e * N + col];
            hout[rb + col] = __float2bfloat16(fmaxf(v, 0.f));
          }
        }
      }
    }
  } else {
    #pragma unroll
    for (int i = 0; i < 4; i++) {
      #pragma unroll
      for (int r = 0; r < 4; r++) {
        int row = wm * 64 + i * 16 + quad * 4 + r;
        if (row < mrows) {
          int tok = rows[start + row];
          float w = roww[start + row];
          size_t ob = (size_t)tok * N;
          #pragma unroll
          for (int j = 0; j < 4; j++) {
            int col = n0 + wn * 64 + j * 16 + col_l;
            float b = addb ? bias[e * N + col] : 0.f;
            float v = (acc[i][j][r] + b) * w;
            unsafeAtomicAdd(&out[ob + col], v);
          }
        }
      }
    }
  }
}

// ---- launch B: GEMM1 (blocks 0..2303) + W2 transpose (blocks 2304..10495) ----
__global__ __launch_bounds__(256)
void k_gemm1_w2t(const bf16* __restrict__ A, const bf16* __restrict__ Bt,
                 const float* __restrict__ bias, const int* __restrict__ cnt,
                 const int* __restrict__ rows, const float* __restrict__ roww,
                 bf16* __restrict__ hout,
                 const float* __restrict__ W2, bf16* __restrict__ w2t) {
  __shared__ __align__(16) char smem[49152];   // gemm: 48 KB; transpose: 16.6 KB
  int b = blockIdx.x;
  if (b < G1BLK) {
    auto& Al = *reinterpret_cast<bf16(*)[3][4096]>((void*)smem);
    auto& Bl = *reinterpret_cast<bf16(*)[3][4096]>((void*)(smem + 24576));
    gemm_tile<1>(A, Bt, bias, cnt, rows, roww, hout, nullptr,
                 DIN, DHID, b, 0, DIN / 32, true, Al, Bl);
  } else {
    int tb = b - G1BLK;
    int e = tb >> 10;           // 1024 blocks per expert (16 x 64)
    int rem = tb & 1023;
    int cx = rem & 15;          // over C = DOUT
    int ry = rem >> 4;          // over R = DHID
    transpose_tile(W2, w2t, DHID, DOUT, cx, ry, e, (float*)smem);
  }
}

// ---- GEMM2: static typed LDS (round-1 codegen), split-K=2 via blockIdx.z ----
__global__ __launch_bounds__(256)
void k_gemm2(const bf16* __restrict__ A, const bf16* __restrict__ Bt,
             const float* __restrict__ bias, const int* __restrict__ cnt,
             const int* __restrict__ rows, const float* __restrict__ roww,
             float* __restrict__ out) {
  __shared__ bf16 Al[3][4096];
  __shared__ bf16 Bl[3][4096];
  int hwid = blockIdx.x + blockIdx.y * gridDim.x;   // 0..575 per split
  gemm_tile<2>(A, Bt, bias, cnt, rows, roww, nullptr, out,
               DHID, DOUT, hwid, blockIdx.z * KH, KH / 32, blockIdx.z == 0,
               Al, Bl);
}

extern "C" void kernel_launch(void* const* d_in, const int* in_sizes, int n_in,
                              void* d_out, int out_size, void* d_ws, size_t ws_size,
                              hipStream_t stream) {
  const float* x  = (const float*)d_in[0];
  const float* W1 = (const float*)d_in[1];
  const float* b1 = (const float*)d_in[2];
  const float* W2 = (const float*)d_in[3];
  const float* b2 = (const float*)d_in[4];
  const float* Wg = (const float*)d_in[5];
  const float* bg = (const float*)d_in[6];
  float* out = (float*)d_out;
  char* ws = (char*)d_ws;

  bf16* xb  = (bf16*)(ws + WS_XB);
  bf16* w1t = (bf16*)(ws + WS_W1T);
  bf16* w2t = (bf16*)(ws + WS_W2T);
  bf16* h   = (bf16*)(ws + WS_H);
  char* meta = ws + WS_META;
  int*   cnt    = (int*)(meta + MO_CNT);
  int*   cur_g  = (int*)(meta + MO_CURG);
  int*   t2i    = (int*)(meta + MO_T2I);
  float* t2w    = (float*)(meta + MO_T2W);
  int*   rows   = (int*)(meta + MO_ROWS);
  float* roww   = (float*)(meta + MO_ROWW);

  hipMemsetAsync(meta, 0, 64, stream);   // cnt[8] + cur_g[8]
  hipMemsetAsync(d_out, 0, (size_t)out_size * sizeof(float), stream);

  // A: gate + W1 transpose fused (1024 + 8192 blocks)
  k_gate_w1t<<<NTOK / 4 + 8192, 256, 0, stream>>>(x, Wg, bg, xb, t2i, t2w, cnt,
                                                  W1, w1t);
  k_scatter<<<NTOK / 256, 256, 0, stream>>>(t2i, t2w, cnt, cur_g, rows, roww);
  // B: GEMM1 + W2 transpose fused (2304 + 8192 blocks)
  k_gemm1_w2t<<<G1BLK + 8192, 256, 0, stream>>>(xb, w1t, b1, cnt, rows, roww, h,
                                                W2, w2t);
  // C: GEMM2, split-K=2
  k_gemm2<<<dim3(TMAX, DOUT / 128, SPLITK), 256, 0, stream>>>(
      h, w2t, b2, cnt, rows, roww, out);
}

// Round 6
// 582.724 us; speedup vs baseline: 1.0955x; 1.0955x over previous
//
#include <hip/hip_runtime.h>
#include <hip/hip_bf16.h>

#define NTOK 4096
#define DIN  1024
#define DHID 4096
#define DOUT 1024
#define NEXP 8
#define TMAX 72   // max 128-row tiles: 8192/128 + 7 partials = 71, +1 slack

typedef __hip_bfloat16 bf16;
typedef short short8 __attribute__((ext_vector_type(8)));
typedef short short4v __attribute__((ext_vector_type(4)));
typedef float floatx4 __attribute__((ext_vector_type(4)));

// s_waitcnt immediates (gfx9 encoding): vmcnt[3:0] @0, expcnt @4, lgkmcnt @8
#define WAIT_VM0 0x0F70   // vmcnt(0), lgkmcnt/expcnt = no-wait
#define WAIT_VM4 0x0F74   // vmcnt(4)

// ---- workspace layout (bytes) ----
#define WS_XB    0ull           // x bf16            [4096*1024]   8.4 MB
#define WS_W1T   8388608ull     // W1^T bf16         [8][4096][1024] 67.1 MB
#define WS_W2T   75497472ull    // W2^T bf16         [8][1024][4096] 67.1 MB
#define WS_H     142606336ull   // h bf16            [8192][4096]  67.1 MB
#define WS_META  209715200ull
// meta region offsets
#define MO_CNT    0     // int[8]   (written by scatter, no memset needed)
#define MO_T2I    1536  // int[4096*2]
#define MO_T2W    34304 // float[4096*2]
#define MO_ROWS   67072 // int[8192]
#define MO_ROWW   99840 // float[8192]

// prep megakernel block ranges
#define PREP_GATE (NTOK / 4)                 // 1024 gate blocks
#define PREP_W1T  8192                       // (DHID/64)*(DIN/64)*NEXP
#define PREP_W2T  8192                       // (DOUT/64)*(DHID/64)*NEXP
#define PREP_OUTZ 256                        // out zeroing blocks
#define PREP_B1   (PREP_GATE)
#define PREP_B2   (PREP_B1 + PREP_W1T)
#define PREP_B3   (PREP_B2 + PREP_W2T)
#define PREP_NBLK (PREP_B3 + PREP_OUTZ)

// async global->LDS, 16 B per lane; LDS dest = wave-uniform base + lane*16
__device__ __forceinline__ void gload16(const bf16* g, bf16* l) {
  __builtin_amdgcn_global_load_lds(
      (const __attribute__((address_space(1))) void*)g,
      (__attribute__((address_space(3))) void*)l, 16, 0, 0);
}

// ---- tile lookup from cnt[8]: returns nt; sets e/start/mrows for `tile` ----
__device__ __forceinline__ int tile_lookup(const int* __restrict__ cnt, int tile,
                                           int& e, int& start, int& mrows) {
  int o = 0, tacc = 0;
  e = -1; start = 0; mrows = 0;
  #pragma unroll
  for (int k = 0; k < 8; k++) {
    int c = cnt[k];
    int nb = (c + 127) >> 7;
    if (e < 0 && tile < tacc + nb) {
      e = k; int r = (tile - tacc) << 7;
      start = o + r; mrows = min(128, c - r);
    }
    tacc += nb; o += c;
  }
  return tacc;
}

// ------- transpose+cast tile: in[R][C] fp32 -> out[C][R] bf16 (one 64x64) -----
// LDS t[c][r] stride 65 (odd -> 2-way alias on both phases, free). Proven r0-r5.
__device__ __forceinline__ void transpose_tile(const float* __restrict__ in,
                                               bf16* __restrict__ out,
                                               int R, int C, int cx, int ry,
                                               int e, float* t) {
  size_t ebase = (size_t)e * R * C;
  int c0 = cx * 64, r0 = ry * 64;
  int tid = threadIdx.x;
  int rr = tid >> 4;            // 0..15
  int cq = (tid & 15) * 4;      // 0,4,...,60
  #pragma unroll
  for (int i = 0; i < 4; i++) {
    int r = rr + i * 16;
    float4 v = *(const float4*)(in + ebase + (size_t)(r0 + r) * C + c0 + cq);
    t[(cq + 0) * 65 + r] = v.x; t[(cq + 1) * 65 + r] = v.y;
    t[(cq + 2) * 65 + r] = v.z; t[(cq + 3) * 65 + r] = v.w;
  }
  __syncthreads();
  int cc = tid >> 3;            // 0..31
  int rq = (tid & 7) * 8;       // 0,8,...,56
  #pragma unroll
  for (int i = 0; i < 2; i++) {
    int c = cc + i * 32;
    union { int4 v; bf16 h[8]; } u;
    #pragma unroll
    for (int j = 0; j < 8; j++) u.h[j] = __float2bfloat16(t[c * 65 + rq + j]);
    *(int4*)(out + ebase + (size_t)(c0 + c) * R + r0 + rq) = u.v;
  }
}

// ------- gating body: softmax -> top2 -> softmax(top2 probs) + x bf16 cast ----
// (no cnt atomics; counting moved to the ballot scatter)
__device__ __forceinline__ void gate_body(const float* __restrict__ x,
                                          const float* __restrict__ Wg,
                                          const float* __restrict__ bg,
                                          bf16* __restrict__ xb,
                                          int* __restrict__ t2i,
                                          float* __restrict__ t2w, int blk) {
  int wave = threadIdx.x >> 6, lane = threadIdx.x & 63;
  int t = blk * 4 + wave;
  const float* xr = x + (size_t)t * DIN;
  bf16* xbr = xb + (size_t)t * DIN;
  float acc[8] = {0.f, 0.f, 0.f, 0.f, 0.f, 0.f, 0.f, 0.f};
  #pragma unroll
  for (int i = 0; i < 4; i++) {
    int d0 = (lane + i * 64) * 4;
    float4 v = *(const float4*)(xr + d0);
    union { short4v s; bf16 h[4]; } u;
    u.h[0] = __float2bfloat16(v.x); u.h[1] = __float2bfloat16(v.y);
    u.h[2] = __float2bfloat16(v.z); u.h[3] = __float2bfloat16(v.w);
    *(short4v*)(xbr + d0) = u.s;
    float xv4[4] = {v.x, v.y, v.z, v.w};
    #pragma unroll
    for (int c = 0; c < 4; c++) {
      const float* wr = Wg + (size_t)(d0 + c) * 8;
      float4 w0 = *(const float4*)wr;
      float4 w1 = *(const float4*)(wr + 4);
      float xv = xv4[c];
      acc[0] += xv * w0.x; acc[1] += xv * w0.y; acc[2] += xv * w0.z; acc[3] += xv * w0.w;
      acc[4] += xv * w1.x; acc[5] += xv * w1.y; acc[6] += xv * w1.z; acc[7] += xv * w1.w;
    }
  }
  #pragma unroll
  for (int off = 32; off; off >>= 1) {
    #pragma unroll
    for (int e = 0; e < 8; e++) acc[e] += __shfl_xor(acc[e], off, 64);
  }
  if (lane == 0) {
    float p[8], m = -1e30f, s = 0.f;
    #pragma unroll
    for (int e = 0; e < 8; e++) { p[e] = acc[e] + bg[e]; m = fmaxf(m, p[e]); }
    #pragma unroll
    for (int e = 0; e < 8; e++) { p[e] = expf(p[e] - m); s += p[e]; }
    float inv = 1.f / s;
    #pragma unroll
    for (int e = 0; e < 8; e++) p[e] *= inv;
    int i0 = 0;
    #pragma unroll
    for (int e = 1; e < 8; e++) if (p[e] > p[i0]) i0 = e;   // ties -> lowest idx
    int i1 = (i0 == 0) ? 1 : 0;
    #pragma unroll
    for (int e = 0; e < 8; e++) if (e != i0 && p[e] > p[i1]) i1 = e;
    float d = expf(p[i1] - p[i0]);           // softmax over the two PROBABILITIES
    float w0 = 1.f / (1.f + d), w1 = d / (1.f + d);
    t2i[2 * t] = i0; t2i[2 * t + 1] = i1;
    t2w[2 * t] = w0; t2w[2 * t + 1] = w1;
  }
}

// ---- launch 1 megakernel: gate + W1T + W2T + out-zero (block-uniform branch) ----
__global__ __launch_bounds__(256)
void k_prep(const float* __restrict__ x, const float* __restrict__ Wg,
            const float* __restrict__ bg, bf16* __restrict__ xb,
            int* __restrict__ t2i, float* __restrict__ t2w,
            const float* __restrict__ W1, bf16* __restrict__ w1t,
            const float* __restrict__ W2, bf16* __restrict__ w2t,
            float* __restrict__ out) {
  __shared__ __align__(16) float tsm[64 * 65];
  int b = blockIdx.x;
  if (b < PREP_B1) {
    gate_body(x, Wg, bg, xb, t2i, t2w, b);
  } else if (b < PREP_B2) {
    int tb = b - PREP_B1;
    int e = tb >> 10;           // 1024 blocks per expert (64 x 16)
    int rem = tb & 1023;
    int cx = rem & 63;          // over C = DHID
    int ry = rem >> 6;          // over R = DIN
    transpose_tile(W1, w1t, DIN, DHID, cx, ry, e, tsm);
  } else if (b < PREP_B3) {
    int tb = b - PREP_B2;
    int e = tb >> 10;           // 1024 blocks per expert (16 x 64)
    int rem = tb & 1023;
    int cx = rem & 15;          // over C = DOUT
    int ry = rem >> 4;          // over R = DHID
    transpose_tile(W2, w2t, DHID, DOUT, cx, ry, e, tsm);
  } else {
    // zero out[NTOK*DOUT] fp32: 65536 threads x 16 float4, coalesced stride
    int t = (b - PREP_B3) * 256 + threadIdx.x;    // 0..65535
    float4 z = {0.f, 0.f, 0.f, 0.f};
    float4* o4 = (float4*)out;
    #pragma unroll
    for (int i = 0; i < 16; i++) o4[i * 65536 + t] = z;
  }
}

// ---- scatter: ONE block, 1024 threads, ballot-based two-level scan ----
// No global atomics, no pre-zeroed state. Wave w owns tokens [w*256,(w+1)*256).
// Stable-ish order (wave-major) is fine: rows/roww pairs travel together.
__global__ __launch_bounds__(1024)
void k_scatter(const int* __restrict__ t2i, const float* __restrict__ t2w,
               int* __restrict__ cnt, int* __restrict__ rows,
               float* __restrict__ roww) {
  __shared__ int wtot[16][8];
  int tid = threadIdx.x, wave = tid >> 6, lane = tid & 63;
  unsigned long long ltmask = (1ull << lane) - 1ull;   // ok for lane 0..63
  int e0c[4], e1c[4], r0c[4], r1c[4];
  int wcnt[8] = {0, 0, 0, 0, 0, 0, 0, 0};
  #pragma unroll
  for (int c = 0; c < 4; c++) {
    int t = wave * 256 + c * 64 + lane;
    int e0 = t2i[2 * t], e1 = t2i[2 * t + 1];
    e0c[c] = e0; e1c[c] = e1;
    r0c[c] = 0; r1c[c] = 0;
    #pragma unroll
    for (int e = 0; e < 8; e++) {
      unsigned long long m0 = __ballot(e0 == e);
      unsigned long long m1 = __ballot(e1 == e);
      int c0 = __popcll(m0), c1 = __popcll(m1);
      if (e0 == e) r0c[c] = wcnt[e] + __popcll(m0 & ltmask);
      if (e1 == e) r1c[c] = wcnt[e] + c0 + __popcll(m1 & ltmask);
      wcnt[e] += c0 + c1;
    }
  }
  if (lane < 8) wtot[wave][lane] = wcnt[lane];
  __syncthreads();
  // per-wave global base for each expert (redundant compute, 128 LDS reads)
  int base_e[8];
  {
    int tote[8];
    #pragma unroll
    for (int e = 0; e < 8; e++) {
      int s = 0;
      #pragma unroll
      for (int w = 0; w < 16; w++) s += wtot[w][e];
      tote[e] = s;
    }
    int a = 0;
    #pragma unroll
    for (int e = 0; e < 8; e++) {
      int p = 0;
      for (int w = 0; w < wave; w++) p += wtot[w][e];
      base_e[e] = a + p;
      a += tote[e];
    }
    if (tid < 8) cnt[tid] = tote[tid];
  }
  #pragma unroll
  for (int c = 0; c < 4; c++) {
    int t = wave * 256 + c * 64 + lane;
    int a0 = base_e[e0c[c]] + r0c[c];
    int a1 = base_e[e1c[c]] + r1c[c];
    rows[a0] = t; roww[a0] = t2w[2 * t];
    rows[a1] = t; roww[a1] = t2w[2 * t + 1];
  }
}

// ---- grouped GEMM tile body, 128x128, BK=32, 4 waves (round-1 proven) ----
// Triple-buffered LDS (48 KB, 3 blk/CU), depth-2 prefetch, counted vmcnt(4),
// chunk-rotation LDS swizzle (0 bank conflicts), XCD-chunked tile swizzle.
// MODE 1: h = relu(x_gathered @ W1T^T + b1), bf16 out
// MODE 2: out[token] += w * (h @ W2T^T + b2), fp32 atomic
template <int MODE>
__device__ __forceinline__ void gemm_tile(
    const bf16* __restrict__ A, const bf16* __restrict__ Bt,
    const float* __restrict__ bias, const int* __restrict__ cnt,
    const int* __restrict__ rows, const float* __restrict__ roww,
    bf16* __restrict__ hout, float* __restrict__ out,
    int K, int N, int hwid,
    bf16 (&Al)[3][4096], bf16 (&Bl)[3][4096]) {
  // XCD-chunked swizzle: XCD c owns tiles [9c,9c+9) x all n-panels, panel-major.
  int xcd = hwid & 7, pos = hwid >> 3;
  int tile = xcd * 9 + pos % 9;
  int e, start, mrows;
  int ntt = tile_lookup(cnt, tile, e, start, mrows);
  if (tile >= ntt) return;   // block-uniform: no barrier divergence
  int n0 = (pos / 9) * 128;
  int tid = threadIdx.x, lane = tid & 63, wave = tid >> 6;
  int wm = wave & 1, wn = wave >> 1;

  int srow = tid >> 2;          // 0..63
  int rot = (srow >> 1) & 3;    // invariant under row+64
  int kc8 = (((tid & 3) - rot) & 3) * 8;   // swizzled source k-octet
  int ra0 = srow, ra1 = 64 + srow;
  int er0 = ra0 < mrows ? ra0 : 0;
  int er1 = ra1 < mrows ? ra1 : 0;
  size_t ga0, ga1;
  if (MODE == 1) {
    ga0 = (size_t)rows[start + er0] * K;
    ga1 = (size_t)rows[start + er1] * K;
  } else {
    ga0 = (size_t)(start + er0) * K;
    ga1 = (size_t)(start + er1) * K;
  }
  const bf16* ap0 = A + ga0 + kc8;
  const bf16* ap1 = A + ga1 + kc8;
  const bf16* bb = Bt + (size_t)e * K * N + (size_t)n0 * K;
  const bf16* bp0 = bb + (size_t)srow * K + kc8;
  const bf16* bp1 = bb + (size_t)(64 + srow) * K + kc8;

  floatx4 zz = {0.f, 0.f, 0.f, 0.f};
  floatx4 acc[4][4];
  #pragma unroll
  for (int i = 0; i < 4; i++)
    #pragma unroll
    for (int j = 0; j < 4; j++) acc[i][j] = zz;

  int fr = lane & 15;
  int ko = (((lane >> 4) + ((fr >> 1) & 3)) & 3) * 8;

#define STAGE(buf, kk)                                    \
  do {                                                    \
    gload16(ap0 + (kk), &Al[buf][tid * 8]);               \
    gload16(ap1 + (kk), &Al[buf][2048 + tid * 8]);        \
    gload16(bp0 + (kk), &Bl[buf][tid * 8]);               \
    gload16(bp1 + (kk), &Bl[buf][2048 + tid * 8]);        \
  } while (0)

  // prologue: 2 tiles in flight
  STAGE(0, 0);
  STAGE(1, 32);

  int nk = K >> 5;
  int cur = 0;
  for (int t = 0; t < nk; ++t) {
    // drain tile t's 4 loads only; tile t+1's 4 stay in flight across MFMAs
    if (t + 1 < nk) __builtin_amdgcn_s_waitcnt(WAIT_VM4);
    else            __builtin_amdgcn_s_waitcnt(WAIT_VM0);
    __builtin_amdgcn_s_barrier();

    short8 af[4], bfr[4];
    #pragma unroll
    for (int i = 0; i < 4; i++)
      af[i] = *(const short8*)&Al[cur][(wm * 64 + i * 16 + fr) * 32 + ko];
    #pragma unroll
    for (int j = 0; j < 4; j++)
      bfr[j] = *(const short8*)&Bl[cur][(wn * 64 + j * 16 + fr) * 32 + ko];

    // issue tile t+2 into buffer (cur+2)%3; WAR-safe (readers done at t-1,
    // separated by this iter's barrier)
    if (t + 2 < nk) {
      int nb = cur + 2; if (nb >= 3) nb -= 3;
      STAGE(nb, (t + 2) * 32);
    }

    #pragma unroll
    for (int i = 0; i < 4; i++)
      #pragma unroll
      for (int j = 0; j < 4; j++)
        acc[i][j] = __builtin_amdgcn_mfma_f32_16x16x32_bf16(af[i], bfr[j], acc[i][j], 0, 0, 0);
    cur = (cur + 1 == 3) ? 0 : cur + 1;
  }
#undef STAGE

  // epilogue: C/D layout col=lane&15, row=(lane>>4)*4+reg
  int col_l = lane & 15, quad = lane >> 4;
  if (MODE == 1) {
    #pragma unroll
    for (int i = 0; i < 4; i++) {
      #pragma unroll
      for (int r = 0; r < 4; r++) {
        int row = wm * 64 + i * 16 + quad * 4 + r;
        if (row < mrows) {
          size_t rb = (size_t)(start + row) * N;
          #pragma unroll
          for (int j = 0; j < 4; j++) {
            int col = n0 + wn * 64 + j * 16 + col_l;
            float v = acc[i][j][r] + bias[e * N + col];
            hout[rb + col] = __float2bfloat16(fmaxf(v, 0.f));
          }
        }
      }
    }
  } else {
    #pragma unroll
    for (int i = 0; i < 4; i++) {
      #pragma unroll
      for (int r = 0; r < 4; r++) {
        int row = wm * 64 + i * 16 + quad * 4 + r;
        if (row < mrows) {
          int tok = rows[start + row];
          float w = roww[start + row];
          size_t ob = (size_t)tok * N;
          #pragma unroll
          for (int j = 0; j < 4; j++) {
            int col = n0 + wn * 64 + j * 16 + col_l;
            float v = (acc[i][j][r] + bias[e * N + col]) * w;
            unsafeAtomicAdd(&out[ob + col], v);
          }
        }
      }
    }
  }
}

// ---- GEMM1: pure, static typed LDS (round-1 codegen) ----
__global__ __launch_bounds__(256)
void k_gemm1(const bf16* __restrict__ A, const bf16* __restrict__ Bt,
             const float* __restrict__ bias, const int* __restrict__ cnt,
             const int* __restrict__ rows, const float* __restrict__ roww,
             bf16* __restrict__ hout) {
  __shared__ bf16 Al[3][4096];
  __shared__ bf16 Bl[3][4096];
  int hwid = blockIdx.x + blockIdx.y * gridDim.x;
  gemm_tile<1>(A, Bt, bias, cnt, rows, roww, hout, nullptr,
               DIN, DHID, hwid, Al, Bl);
}

// ---- GEMM2: pure, static typed LDS, no split-K ----
__global__ __launch_bounds__(256)
void k_gemm2(const bf16* __restrict__ A, const bf16* __restrict__ Bt,
             const float* __restrict__ bias, const int* __restrict__ cnt,
             const int* __restrict__ rows, const float* __restrict__ roww,
             float* __restrict__ out) {
  __shared__ bf16 Al[3][4096];
  __shared__ bf16 Bl[3][4096];
  int hwid = blockIdx.x + blockIdx.y * gridDim.x;
  gemm_tile<2>(A, Bt, bias, cnt, rows, roww, nullptr, out,
               DHID, DOUT, hwid, Al, Bl);
}

extern "C" void kernel_launch(void* const* d_in, const int* in_sizes, int n_in,
                              void* d_out, int out_size, void* d_ws, size_t ws_size,
                              hipStream_t stream) {
  const float* x  = (const float*)d_in[0];
  const float* W1 = (const float*)d_in[1];
  const float* b1 = (const float*)d_in[2];
  const float* W2 = (const float*)d_in[3];
  const float* b2 = (const float*)d_in[4];
  const float* Wg = (const float*)d_in[5];
  const float* bg = (const float*)d_in[6];
  float* out = (float*)d_out;
  char* ws = (char*)d_ws;

  bf16* xb  = (bf16*)(ws + WS_XB);
  bf16* w1t = (bf16*)(ws + WS_W1T);
  bf16* w2t = (bf16*)(ws + WS_W2T);
  bf16* h   = (bf16*)(ws + WS_H);
  char* meta = ws + WS_META;
  int*   cnt  = (int*)(meta + MO_CNT);
  int*   t2i  = (int*)(meta + MO_T2I);
  float* t2w  = (float*)(meta + MO_T2W);
  int*   rows = (int*)(meta + MO_ROWS);
  float* roww = (float*)(meta + MO_ROWW);

  // L1: gate + W1T + W2T + out-zero (one launch, no memsets)
  k_prep<<<PREP_NBLK, 256, 0, stream>>>(x, Wg, bg, xb, t2i, t2w,
                                        W1, w1t, W2, w2t, out);
  // L2: ballot scatter (1 block, writes cnt + rows + roww)
  k_scatter<<<1, 1024, 0, stream>>>(t2i, t2w, cnt, rows, roww);
  // L3: GEMM1
  k_gemm1<<<dim3(TMAX, DHID / 128), 256, 0, stream>>>(
      xb, w1t, b1, cnt, rows, roww, h);
  // L4: GEMM2
  k_gemm2<<<dim3(TMAX, DOUT / 128), 256, 0, stream>>>(
      h, w2t, b2, cnt, rows, roww, out);
}